// Round 24
// baseline (165.159 us; speedup 1.0000x reference)
//
#include <hip/hip_runtime.h>
#include <math.h>

#define NUM_TOK 2048
#define HDIM 1024
#define IDIM 2048
#define NEXP 8
#define MAX_ROWS 6144   // 256-aligned segments

typedef __attribute__((ext_vector_type(8))) short bf16x8;
typedef __attribute__((ext_vector_type(4))) float f32x4;

// ---- workspace offsets (bytes) ----
#define OFF_IDX   0u
#define OFF_RW    16384u
#define OFF_SEG   32832u
#define OFF_ROWS  33024u
#define OFF_XB    131072u
#define OFF_ACT   41943040u

// Counted barrier (gemm1 only): retire the older gld_lds staging + ds ops,
// leave the newer weight register-loads in flight across the barrier.
#define BARC(n) do { \
    asm volatile("s_waitcnt vmcnt(" #n ") lgkmcnt(0)" ::: "memory"); \
    __builtin_amdgcn_s_barrier(); \
  } while (0)

__device__ __forceinline__ unsigned short f2bf(float f) {
  __bf16 b = (__bf16)f;
  return __builtin_bit_cast(unsigned short, b);
}

__device__ __forceinline__ unsigned pk2(float lo, float hi) {
  __bf16 a = (__bf16)lo, b = (__bf16)hi;
  return (unsigned)__builtin_bit_cast(unsigned short, a) |
         ((unsigned)__builtin_bit_cast(unsigned short, b) << 16);
}

__device__ __forceinline__ void gld16(const void* g, void* l) {
  __builtin_amdgcn_global_load_lds(
      (const __attribute__((address_space(1))) void*)g,
      (__attribute__((address_space(3))) void*)l, 16, 0, 0);
}

// router + out-zeroing + rowsv pre-fill
__global__ void k_router(const float* __restrict__ x, const float* __restrict__ wg,
                         unsigned short* __restrict__ xb,
                         int* __restrict__ idx, float* __restrict__ rw,
                         float* __restrict__ out, int* __restrict__ rowsv) {
  {
    const int i = blockIdx.x * blockDim.x + threadIdx.x;
#pragma unroll
    for (int q = 0; q < 4; ++q)
      ((float4*)out)[(size_t)i * 4 + q] = make_float4(0.f, 0.f, 0.f, 0.f);
    if (i < MAX_ROWS) rowsv[i] = -1;
  }
  const int wave = threadIdx.x >> 6, lane = threadIdx.x & 63;
  const int t = blockIdx.x * 4 + wave;
  const float2* __restrict__ xr = (const float2*)(x + (size_t)t * HDIM);
  unsigned* __restrict__ xbr = (unsigned*)(xb + (size_t)t * HDIM);
  float acc[8];
#pragma unroll
  for (int q = 0; q < 8; ++q) acc[q] = 0.f;
#pragma unroll
  for (int j = 0; j < 8; ++j) {
    const int h2 = lane + (j << 6);
    const float2 v = xr[h2];
    const float* wrow = wg + (size_t)h2 * 16;
    const float4 a0 = *(const float4*)(wrow);
    const float4 a1 = *(const float4*)(wrow + 4);
    const float4 b0 = *(const float4*)(wrow + 8);
    const float4 b1 = *(const float4*)(wrow + 12);
    acc[0] = fmaf(v.x, a0.x, fmaf(v.y, b0.x, acc[0]));
    acc[1] = fmaf(v.x, a0.y, fmaf(v.y, b0.y, acc[1]));
    acc[2] = fmaf(v.x, a0.z, fmaf(v.y, b0.z, acc[2]));
    acc[3] = fmaf(v.x, a0.w, fmaf(v.y, b0.w, acc[3]));
    acc[4] = fmaf(v.x, a1.x, fmaf(v.y, b1.x, acc[4]));
    acc[5] = fmaf(v.x, a1.y, fmaf(v.y, b1.y, acc[5]));
    acc[6] = fmaf(v.x, a1.z, fmaf(v.y, b1.z, acc[6]));
    acc[7] = fmaf(v.x, a1.w, fmaf(v.y, b1.w, acc[7]));
    xbr[h2] = pk2(v.x, v.y);
  }
#pragma unroll
  for (int q = 0; q < 8; ++q) {
#pragma unroll
    for (int off = 32; off >= 1; off >>= 1)
      acc[q] += __shfl_xor(acc[q], off, 64);
  }
  if (lane == 0) {
    int i0 = 0; float v0 = acc[0];
#pragma unroll
    for (int q = 1; q < 8; ++q)
      if (acc[q] > v0) { v0 = acc[q]; i0 = q; }
    int i1 = -1; float v1 = -3.4e38f;
#pragma unroll
    for (int q = 0; q < 8; ++q)
      if (q != i0 && acc[q] > v1) { v1 = acc[q]; i1 = q; }
    const float e1 = expf(v1 - v0);
    const float inv = 1.f / (1.f + e1);
    idx[2 * t] = i0; idx[2 * t + 1] = i1;
    rw[2 * t] = inv; rw[2 * t + 1] = e1 * inv;
  }
}

// single block: histogram -> 256-aligned segments -> scatter
__global__ void k_segscatter(const int* __restrict__ idx, int* __restrict__ seg,
                             int* __restrict__ rowsv) {
  __shared__ int hist[NEXP], cur[NEXP], sseg[NEXP];
  const int tid = threadIdx.x;
  if (tid < NEXP) { hist[tid] = 0; cur[tid] = 0; }
  __syncthreads();
  for (int s = tid; s < 2 * NUM_TOK; s += 256) atomicAdd(&hist[idx[s]], 1);
  __syncthreads();
  if (tid == 0) {
    int s = 0;
    for (int q = 0; q < NEXP; ++q) {
      seg[q] = s; sseg[q] = s;
      s += ((hist[q] + 255) / 256) * 256;
    }
    seg[NEXP] = s;
  }
  __syncthreads();
  for (int s = tid; s < 2 * NUM_TOK; s += 256) {
    const int e = idx[s];
    const int p = atomicAdd(&cur[e], 1);
    rowsv[sseg[e] + p] = s;
  }
}

// grouped GEMM1: act = silu(x@W1)*(x@W3). 512 thr, BM=256, BK=32, 2-deep
// register prefetch; counted barrier keeps weight loads in flight across legs.
// Tail clamp loads k0=0 (L2-hot) to keep vmcnt FIFO counts uniform for BARC(2).
__launch_bounds__(512, 4)
__global__ void k_gemm1(const unsigned short* __restrict__ xb,
                        const float* __restrict__ W1f,
                        const float* __restrict__ W3f,
                        const int* __restrict__ seg, const int* __restrict__ rowsv,
                        unsigned short* __restrict__ act) {
  __shared__ __align__(16) unsigned short As[2][256 * 32];
  __shared__ __align__(16) unsigned short Bs[2][128 * 32];
  const int tid = threadIdx.x;
  const int w = tid >> 6, l = tid & 63;
  const int m0 = blockIdx.y * 256;
  const int total = seg[NEXP];
  if (m0 >= total) return;
  int e = 0;
#pragma unroll
  for (int q = 1; q < NEXP; ++q) if (m0 >= seg[q]) e = q;
  const int n0 = blockIdx.x * 64;

  const int swzA = ((tid & 3) ^ ((tid >> 4) & 3) ^ ((tid >> 3) & 3)) * 8;
  size_t aOff[2];
#pragma unroll
  for (int q = 0; q < 2; ++q) {
    const int r = rowsv[m0 + q * 128 + (tid >> 2)];
    const int tk = (r < 0) ? 0 : (r >> 1);
    aOff[q] = (size_t)tk * HDIM + swzA;
  }
  auto stageA = [&](int buf, int k0) {
#pragma unroll
    for (int q = 0; q < 2; ++q)
      gld16(xb + aOff[q] + k0, &As[buf][(q * 128 + (tid >> 2)) * 32 + (tid & 3) * 8]);
  };

  const int s  = tid >> 8;            // 0=W1, 1=W3
  const int kk = (tid >> 4) & 15;
  const int ng = tid & 15;
  const float* __restrict__ Wf = s ? W3f : W1f;
  const size_t bBase = (size_t)e * HDIM * IDIM + (size_t)(2 * kk) * IDIM + n0 + ng * 4;

  struct Bregs { float4 v0, v1; };
  auto loadB = [&](Bregs& p, int k0) {
    const size_t b = bBase + (size_t)k0 * IDIM;
    p.v0 = *(const float4*)(Wf + b);
    p.v1 = *(const float4*)(Wf + b + IDIM);
  };
  auto writeB = [&](int buf, const Bregs& p) {
    unsigned* Bd = (unsigned*)&Bs[buf][0];
    const float a0[4] = {p.v0.x, p.v0.y, p.v0.z, p.v0.w};
    const float a1[4] = {p.v1.x, p.v1.y, p.v1.z, p.v1.w};
#pragma unroll
    for (int i = 0; i < 4; ++i) {
      const int r = s * 64 + ng * 4 + i;
      const int f = ((r >> 2) & 3) ^ ((r >> 1) & 3);
      const int d = (((kk >> 2) ^ f) << 2) + (kk & 3);
      Bd[r * 16 + d] = pk2(a0[i], a1[i]);
    }
  };

  f32x4 acc[2][8];
#pragma unroll
  for (int m = 0; m < 2; ++m)
#pragma unroll
    for (int nf = 0; nf < 8; ++nf) acc[m][nf] = (f32x4)0.f;

  const int rslot = ((l >> 4) ^ ((l >> 2) & 3) ^ ((l >> 1) & 3)) * 8;
  const int arow = (w * 32 + (l & 15)) * 32 + rslot;
  auto mfmaStep = [&](int buf) {
    __builtin_amdgcn_s_setprio(1);
    const bf16x8 a0 = *(const bf16x8*)&As[buf][arow];
    const bf16x8 a1 = *(const bf16x8*)&As[buf][arow + 16 * 32];
#pragma unroll
    for (int nf = 0; nf < 8; ++nf) {
      const bf16x8 b = *(const bf16x8*)&Bs[buf][(nf * 16 + (l & 15)) * 32 + rslot];
      acc[0][nf] = __builtin_amdgcn_mfma_f32_16x16x32_bf16(a0, b, acc[0][nf], 0, 0, 0);
      acc[1][nf] = __builtin_amdgcn_mfma_f32_16x16x32_bf16(a1, b, acc[1][nf], 0, 0, 0);
    }
    __builtin_amdgcn_s_setprio(0);
  };

  const int NT = HDIM / 32;   // 32, even
  Bregs pA, pB;
  loadB(pA, 0);
  stageA(0, 0);
  loadB(pB, 32);
  writeB(0, pA);
  BARC(2);

  for (int t = 0; t < NT; t += 2) {
    stageA(1, (t + 1) * 32);
    loadB(pA, (t + 2 < NT) ? (t + 2) * 32 : 0);
    __builtin_amdgcn_sched_barrier(0);
    mfmaStep(0);
    writeB(1, pB);
    BARC(2);
    if (t + 2 < NT) stageA(0, (t + 2) * 32);
    loadB(pB, (t + 3 < NT) ? (t + 3) * 32 : 0);
    __builtin_amdgcn_sched_barrier(0);
    mfmaStep(1);
    if (t + 2 < NT) writeB(0, pA);
    BARC(2);
  }

  const int rbase = m0 + w * 32 + (l >> 4) * 4;
  const int cbase = n0 + (l & 15);
#pragma unroll
  for (int m = 0; m < 2; ++m)
#pragma unroll
    for (int p = 0; p < 4; ++p) {
      const f32x4 up = acc[m][p];
      const f32x4 gt = acc[m][p + 4];
#pragma unroll
      for (int r = 0; r < 4; ++r) {
        const float u = up[r];
        const float sv = (u / (1.f + expf(-u))) * gt[r];
        act[(size_t)(rbase + m * 16 + r) * IDIM + cbase + p * 16] = f2bf(sv);
      }
    }
}

// grouped GEMM2 (plain __syncthreads, launch_bounds (256,2)):
// out[token] += rw[slot] * (act[slot-row] @ W2[e]) via atomicAdd
// (exactly 2 commutative fp32 adds per element -> deterministic).
__launch_bounds__(256, 2)
__global__ void k_gemm2(const unsigned short* __restrict__ act,
                        const float* __restrict__ W2f,
                        const int* __restrict__ seg, const int* __restrict__ rowsv,
                        const float* __restrict__ rw,
                        float* __restrict__ out) {
  __shared__ __align__(16) unsigned short As[2][128 * 32];
  __shared__ __align__(16) unsigned short Bs[2][128 * 32];
  const int tid = threadIdx.x;
  const int w = tid >> 6, l = tid & 63;
  const int m0 = blockIdx.y * 128;
  const int total = seg[NEXP];
  if (m0 >= total) return;
  int e = 0;
#pragma unroll
  for (int q = 1; q < NEXP; ++q) if (m0 >= seg[q]) e = q;
  const int n0 = blockIdx.x * 128;

  const int swzA = ((tid & 3) ^ ((tid >> 4) & 3) ^ ((tid >> 3) & 3)) * 8;
  size_t aOff[2];
#pragma unroll
  for (int q = 0; q < 2; ++q)
    aOff[q] = (size_t)(m0 + q * 64 + (tid >> 2)) * IDIM + swzA;

  const int kk = tid >> 4;
  const int ng = tid & 15;
  const size_t bBase = (size_t)e * IDIM * HDIM + (size_t)(2 * kk) * HDIM + n0 + ng * 4;

  struct Bregs { float4 a0, a1, b0, b1; };
  auto loadB = [&](Bregs& p, int k0) {
    const size_t b = bBase + (size_t)k0 * HDIM;
    p.a0 = *(const float4*)(W2f + b);
    p.a1 = *(const float4*)(W2f + b + HDIM);
    p.b0 = *(const float4*)(W2f + b + 64);
    p.b1 = *(const float4*)(W2f + b + HDIM + 64);
  };
  auto writeB = [&](int buf, const Bregs& p) {
    unsigned* Bd = (unsigned*)&Bs[buf][0];
    const float q00[4] = {p.a0.x, p.a0.y, p.a0.z, p.a0.w};
    const float q01[4] = {p.a1.x, p.a1.y, p.a1.z, p.a1.w};
    const float q10[4] = {p.b0.x, p.b0.y, p.b0.z, p.b0.w};
    const float q11[4] = {p.b1.x, p.b1.y, p.b1.z, p.b1.w};
#pragma unroll
    for (int i = 0; i < 4; ++i) {
      const int rm = ng * 4 + i;
      const int f = ((rm >> 2) & 3) ^ ((rm >> 1) & 3);
      const int d = (((kk >> 2) ^ f) << 2) + (kk & 3);
      Bd[rm * 16 + d]        = pk2(q00[i], q01[i]);
      Bd[(rm + 64) * 16 + d] = pk2(q10[i], q11[i]);
    }
  };
  auto stageA = [&](int buf, int k0) {
#pragma unroll
    for (int q = 0; q < 2; ++q)
      gld16(act + aOff[q] + k0, &As[buf][(q * 64 + (tid >> 2)) * 32]);
  };

  f32x4 acc[2][8];
#pragma unroll
  for (int mf = 0; mf < 2; ++mf)
#pragma unroll
    for (int nf = 0; nf < 8; ++nf) acc[mf][nf] = (f32x4)0.f;

  const int rslot = ((l >> 4) ^ ((l >> 2) & 3) ^ ((l >> 1) & 3)) * 8;
  const int arow = (w * 32 + (l & 15)) * 32 + rslot;
  auto mfmaStep = [&](int buf) {
    __builtin_amdgcn_s_setprio(1);
    const bf16x8 a0 = *(const bf16x8*)&As[buf][arow];
    const bf16x8 a1 = *(const bf16x8*)&As[buf][arow + 16 * 32];
#pragma unroll
    for (int nf = 0; nf < 8; ++nf) {
      const bf16x8 b = *(const bf16x8*)&Bs[buf][(nf * 16 + (l & 15)) * 32 + rslot];
      acc[0][nf] = __builtin_amdgcn_mfma_f32_16x16x32_bf16(a0, b, acc[0][nf], 0, 0, 0);
      acc[1][nf] = __builtin_amdgcn_mfma_f32_16x16x32_bf16(a1, b, acc[1][nf], 0, 0, 0);
    }
    __builtin_amdgcn_s_setprio(0);
  };

  Bregs pA, pB;
  loadB(pA, 0);
  stageA(0, 0);
  loadB(pB, 32);
  writeB(0, pA);
  __syncthreads();

  const int NT = IDIM / 32;   // 64, even
  for (int t = 0; t < NT; t += 2) {
    if (t + 2 < NT) loadB(pA, (t + 2) * 32);
    stageA(1, (t + 1) * 32);
    __builtin_amdgcn_sched_barrier(0);
    mfmaStep(0);
    writeB(1, pB);
    __syncthreads();
    if (t + 3 < NT) loadB(pB, (t + 3) * 32);
    if (t + 2 < NT) stageA(0, (t + 2) * 32);
    __builtin_amdgcn_sched_barrier(0);
    mfmaStep(1);
    if (t + 2 < NT) writeB(0, pA);
    __syncthreads();
  }

  const int rbase = m0 + w * 32 + (l >> 4) * 4;
  const int cbase = n0 + (l & 15);
#pragma unroll
  for (int mf = 0; mf < 2; ++mf)
#pragma unroll
    for (int r = 0; r < 4; ++r) {
      const int row = rbase + mf * 16 + r;
      const int slot = rowsv[row];
      if (slot >= 0) {
        const float wgt = rw[slot];
        float* op = out + (size_t)(slot >> 1) * HDIM + cbase;
#pragma unroll
        for (int nf = 0; nf < 8; ++nf)
          atomicAdd(op + nf * 16, acc[mf][nf][r] * wgt);
      }
    }
}

extern "C" void kernel_launch(void* const* d_in, const int* in_sizes, int n_in,
                              void* d_out, int out_size, void* d_ws, size_t ws_size,
                              hipStream_t stream) {
  const float* x  = (const float*)d_in[0];
  const float* Wg = (const float*)d_in[1];
  const float* W1 = (const float*)d_in[2];   // (E, H, I) fp32
  const float* W2 = (const float*)d_in[3];   // (E, I, H) fp32
  const float* W3 = (const float*)d_in[4];   // (E, H, I) fp32
  float* out = (float*)d_out;
  char* ws = (char*)d_ws;
  int*   idx  = (int*)(ws + OFF_IDX);
  float* rw   = (float*)(ws + OFF_RW);
  int*   seg  = (int*)(ws + OFF_SEG);
  int*   rowsv= (int*)(ws + OFF_ROWS);
  unsigned short* xb  = (unsigned short*)(ws + OFF_XB);
  unsigned short* act = (unsigned short*)(ws + OFF_ACT);

  k_router<<<NUM_TOK / 4, 256, 0, stream>>>(x, Wg, xb, idx, rw, out, rowsv);
  k_segscatter<<<1, 256, 0, stream>>>(idx, seg, rowsv);
  k_gemm1<<<dim3(IDIM / 64, MAX_ROWS / 256), 512, 0, stream>>>(xb, W1, W3, seg, rowsv, act);
  k_gemm2<<<dim3(HDIM / 128, MAX_ROWS / 128), 256, 0, stream>>>(act, W2, seg, rowsv, rw, out);
}

// Round 25
// 158.831 us; speedup vs baseline: 1.0398x; 1.0398x over previous
//
#include <hip/hip_runtime.h>
#include <math.h>

#define NUM_TOK 2048
#define HDIM 1024
#define IDIM 2048
#define NEXP 8
#define MAX_ROWS 6144   // 256-aligned segments

typedef __attribute__((ext_vector_type(8))) short bf16x8;
typedef __attribute__((ext_vector_type(4))) float f32x4;

// ---- workspace offsets (bytes) ----
#define OFF_IDX   0u
#define OFF_RW    16384u
#define OFF_SEG   32832u
#define OFF_ROWS  33024u
#define OFF_XB    131072u
#define OFF_ACT   41943040u

__device__ __forceinline__ unsigned short f2bf(float f) {
  __bf16 b = (__bf16)f;
  return __builtin_bit_cast(unsigned short, b);
}

__device__ __forceinline__ unsigned pk2(float lo, float hi) {
  __bf16 a = (__bf16)lo, b = (__bf16)hi;
  return (unsigned)__builtin_bit_cast(unsigned short, a) |
         ((unsigned)__builtin_bit_cast(unsigned short, b) << 16);
}

__device__ __forceinline__ void gld16(const void* g, void* l) {
  __builtin_amdgcn_global_load_lds(
      (const __attribute__((address_space(1))) void*)g,
      (__attribute__((address_space(3))) void*)l, 16, 0, 0);
}

// router + out-zeroing + rowsv pre-fill
__global__ void k_router(const float* __restrict__ x, const float* __restrict__ wg,
                         unsigned short* __restrict__ xb,
                         int* __restrict__ idx, float* __restrict__ rw,
                         float* __restrict__ out, int* __restrict__ rowsv) {
  {
    const int i = blockIdx.x * blockDim.x + threadIdx.x;
#pragma unroll
    for (int q = 0; q < 4; ++q)
      ((float4*)out)[(size_t)i * 4 + q] = make_float4(0.f, 0.f, 0.f, 0.f);
    if (i < MAX_ROWS) rowsv[i] = -1;
  }
  const int wave = threadIdx.x >> 6, lane = threadIdx.x & 63;
  const int t = blockIdx.x * 4 + wave;
  const float2* __restrict__ xr = (const float2*)(x + (size_t)t * HDIM);
  unsigned* __restrict__ xbr = (unsigned*)(xb + (size_t)t * HDIM);
  float acc[8];
#pragma unroll
  for (int q = 0; q < 8; ++q) acc[q] = 0.f;
#pragma unroll
  for (int j = 0; j < 8; ++j) {
    const int h2 = lane + (j << 6);
    const float2 v = xr[h2];
    const float* wrow = wg + (size_t)h2 * 16;
    const float4 a0 = *(const float4*)(wrow);
    const float4 a1 = *(const float4*)(wrow + 4);
    const float4 b0 = *(const float4*)(wrow + 8);
    const float4 b1 = *(const float4*)(wrow + 12);
    acc[0] = fmaf(v.x, a0.x, fmaf(v.y, b0.x, acc[0]));
    acc[1] = fmaf(v.x, a0.y, fmaf(v.y, b0.y, acc[1]));
    acc[2] = fmaf(v.x, a0.z, fmaf(v.y, b0.z, acc[2]));
    acc[3] = fmaf(v.x, a0.w, fmaf(v.y, b0.w, acc[3]));
    acc[4] = fmaf(v.x, a1.x, fmaf(v.y, b1.x, acc[4]));
    acc[5] = fmaf(v.x, a1.y, fmaf(v.y, b1.y, acc[5]));
    acc[6] = fmaf(v.x, a1.z, fmaf(v.y, b1.z, acc[6]));
    acc[7] = fmaf(v.x, a1.w, fmaf(v.y, b1.w, acc[7]));
    xbr[h2] = pk2(v.x, v.y);
  }
#pragma unroll
  for (int q = 0; q < 8; ++q) {
#pragma unroll
    for (int off = 32; off >= 1; off >>= 1)
      acc[q] += __shfl_xor(acc[q], off, 64);
  }
  if (lane == 0) {
    int i0 = 0; float v0 = acc[0];
#pragma unroll
    for (int q = 1; q < 8; ++q)
      if (acc[q] > v0) { v0 = acc[q]; i0 = q; }
    int i1 = -1; float v1 = -3.4e38f;
#pragma unroll
    for (int q = 0; q < 8; ++q)
      if (q != i0 && acc[q] > v1) { v1 = acc[q]; i1 = q; }
    const float e1 = expf(v1 - v0);
    const float inv = 1.f / (1.f + e1);
    idx[2 * t] = i0; idx[2 * t + 1] = i1;
    rw[2 * t] = inv; rw[2 * t + 1] = e1 * inv;
  }
}

// single block: histogram -> 256-aligned segments -> scatter
__global__ void k_segscatter(const int* __restrict__ idx, int* __restrict__ seg,
                             int* __restrict__ rowsv) {
  __shared__ int hist[NEXP], cur[NEXP], sseg[NEXP];
  const int tid = threadIdx.x;
  if (tid < NEXP) { hist[tid] = 0; cur[tid] = 0; }
  __syncthreads();
  for (int s = tid; s < 2 * NUM_TOK; s += 256) atomicAdd(&hist[idx[s]], 1);
  __syncthreads();
  if (tid == 0) {
    int s = 0;
    for (int q = 0; q < NEXP; ++q) {
      seg[q] = s; sseg[q] = s;
      s += ((hist[q] + 255) / 256) * 256;
    }
    seg[NEXP] = s;
  }
  __syncthreads();
  for (int s = tid; s < 2 * NUM_TOK; s += 256) {
    const int e = idx[s];
    const int p = atomicAdd(&cur[e], 1);
    rowsv[sseg[e] + p] = s;
  }
}

// grouped GEMM1: act = silu(x@W1)*(x@W3).
// 512 thr, BM=256, BK=32, 2-deep register prefetch + HW cvt + setprio.
__launch_bounds__(512, 4)
__global__ void k_gemm1(const unsigned short* __restrict__ xb,
                        const float* __restrict__ W1f,
                        const float* __restrict__ W3f,
                        const int* __restrict__ seg, const int* __restrict__ rowsv,
                        unsigned short* __restrict__ act) {
  __shared__ __align__(16) unsigned short As[2][256 * 32];
  __shared__ __align__(16) unsigned short Bs[2][128 * 32];
  const int tid = threadIdx.x;
  const int w = tid >> 6, l = tid & 63;
  const int m0 = blockIdx.y * 256;
  const int total = seg[NEXP];
  if (m0 >= total) return;
  int e = 0;
#pragma unroll
  for (int q = 1; q < NEXP; ++q) if (m0 >= seg[q]) e = q;
  const int n0 = blockIdx.x * 64;

  const int swzA = ((tid & 3) ^ ((tid >> 4) & 3) ^ ((tid >> 3) & 3)) * 8;
  size_t aOff[2];
#pragma unroll
  for (int q = 0; q < 2; ++q) {
    const int r = rowsv[m0 + q * 128 + (tid >> 2)];
    const int tk = (r < 0) ? 0 : (r >> 1);
    aOff[q] = (size_t)tk * HDIM + swzA;
  }
  auto stageA = [&](int buf, int k0) {
#pragma unroll
    for (int q = 0; q < 2; ++q)
      gld16(xb + aOff[q] + k0, &As[buf][(q * 128 + (tid >> 2)) * 32 + (tid & 3) * 8]);
  };

  const int s  = tid >> 8;            // 0=W1, 1=W3
  const int kk = (tid >> 4) & 15;
  const int ng = tid & 15;
  const float* __restrict__ Wf = s ? W3f : W1f;
  const size_t bBase = (size_t)e * HDIM * IDIM + (size_t)(2 * kk) * IDIM + n0 + ng * 4;

  struct Bregs { float4 v0, v1; };
  auto loadB = [&](Bregs& p, int k0) {
    const size_t b = bBase + (size_t)k0 * IDIM;
    p.v0 = *(const float4*)(Wf + b);
    p.v1 = *(const float4*)(Wf + b + IDIM);
  };
  auto writeB = [&](int buf, const Bregs& p) {
    unsigned* Bd = (unsigned*)&Bs[buf][0];
    const float a0[4] = {p.v0.x, p.v0.y, p.v0.z, p.v0.w};
    const float a1[4] = {p.v1.x, p.v1.y, p.v1.z, p.v1.w};
#pragma unroll
    for (int i = 0; i < 4; ++i) {
      const int r = s * 64 + ng * 4 + i;
      const int f = ((r >> 2) & 3) ^ ((r >> 1) & 3);
      const int d = (((kk >> 2) ^ f) << 2) + (kk & 3);
      Bd[r * 16 + d] = pk2(a0[i], a1[i]);
    }
  };

  f32x4 acc[2][8];
#pragma unroll
  for (int m = 0; m < 2; ++m)
#pragma unroll
    for (int nf = 0; nf < 8; ++nf) acc[m][nf] = (f32x4)0.f;

  const int rslot = ((l >> 4) ^ ((l >> 2) & 3) ^ ((l >> 1) & 3)) * 8;
  const int arow = (w * 32 + (l & 15)) * 32 + rslot;
  auto mfmaStep = [&](int buf) {
    __builtin_amdgcn_s_setprio(1);
    const bf16x8 a0 = *(const bf16x8*)&As[buf][arow];
    const bf16x8 a1 = *(const bf16x8*)&As[buf][arow + 16 * 32];
#pragma unroll
    for (int nf = 0; nf < 8; ++nf) {
      const bf16x8 b = *(const bf16x8*)&Bs[buf][(nf * 16 + (l & 15)) * 32 + rslot];
      acc[0][nf] = __builtin_amdgcn_mfma_f32_16x16x32_bf16(a0, b, acc[0][nf], 0, 0, 0);
      acc[1][nf] = __builtin_amdgcn_mfma_f32_16x16x32_bf16(a1, b, acc[1][nf], 0, 0, 0);
    }
    __builtin_amdgcn_s_setprio(0);
  };

  Bregs pA, pB;
  loadB(pA, 0);
  stageA(0, 0);
  loadB(pB, 32);
  writeB(0, pA);
  __syncthreads();

  const int NT = HDIM / 32;   // 32, even
  for (int t = 0; t < NT; t += 2) {
    if (t + 2 < NT) loadB(pA, (t + 2) * 32);
    stageA(1, (t + 1) * 32);
    __builtin_amdgcn_sched_barrier(0);
    mfmaStep(0);
    writeB(1, pB);
    __syncthreads();
    if (t + 3 < NT) loadB(pB, (t + 3) * 32);
    if (t + 2 < NT) stageA(0, (t + 2) * 32);
    __builtin_amdgcn_sched_barrier(0);
    mfmaStep(1);
    if (t + 2 < NT) writeB(0, pA);
    __syncthreads();
  }

  const int rbase = m0 + w * 32 + (l >> 4) * 4;
  const int cbase = n0 + (l & 15);
#pragma unroll
  for (int m = 0; m < 2; ++m)
#pragma unroll
    for (int p = 0; p < 4; ++p) {
      const f32x4 up = acc[m][p];
      const f32x4 gt = acc[m][p + 4];
#pragma unroll
      for (int r = 0; r < 4; ++r) {
        const float u = up[r];
        const float sv = (u / (1.f + expf(-u))) * gt[r];
        act[(size_t)(rbase + m * 16 + r) * IDIM + cbase + p * 16] = f2bf(sv);
      }
    }
}

// grouped GEMM2 (plain __syncthreads, launch_bounds (256,2)):
// out[token] += rw[slot] * (act[slot-row] @ W2[e]) via atomicAdd
// (exactly 2 commutative fp32 adds per element -> deterministic).
__launch_bounds__(256, 2)
__global__ void k_gemm2(const unsigned short* __restrict__ act,
                        const float* __restrict__ W2f,
                        const int* __restrict__ seg, const int* __restrict__ rowsv,
                        const float* __restrict__ rw,
                        float* __restrict__ out) {
  __shared__ __align__(16) unsigned short As[2][128 * 32];
  __shared__ __align__(16) unsigned short Bs[2][128 * 32];
  const int tid = threadIdx.x;
  const int w = tid >> 6, l = tid & 63;
  const int m0 = blockIdx.y * 128;
  const int total = seg[NEXP];
  if (m0 >= total) return;
  int e = 0;
#pragma unroll
  for (int q = 1; q < NEXP; ++q) if (m0 >= seg[q]) e = q;
  const int n0 = blockIdx.x * 128;

  const int swzA = ((tid & 3) ^ ((tid >> 4) & 3) ^ ((tid >> 3) & 3)) * 8;
  size_t aOff[2];
#pragma unroll
  for (int q = 0; q < 2; ++q)
    aOff[q] = (size_t)(m0 + q * 64 + (tid >> 2)) * IDIM + swzA;

  const int kk = tid >> 4;
  const int ng = tid & 15;
  const size_t bBase = (size_t)e * IDIM * HDIM + (size_t)(2 * kk) * HDIM + n0 + ng * 4;

  struct Bregs { float4 a0, a1, b0, b1; };
  auto loadB = [&](Bregs& p, int k0) {
    const size_t b = bBase + (size_t)k0 * HDIM;
    p.a0 = *(const float4*)(W2f + b);
    p.a1 = *(const float4*)(W2f + b + HDIM);
    p.b0 = *(const float4*)(W2f + b + 64);
    p.b1 = *(const float4*)(W2f + b + HDIM + 64);
  };
  auto writeB = [&](int buf, const Bregs& p) {
    unsigned* Bd = (unsigned*)&Bs[buf][0];
    const float q00[4] = {p.a0.x, p.a0.y, p.a0.z, p.a0.w};
    const float q01[4] = {p.a1.x, p.a1.y, p.a1.z, p.a1.w};
    const float q10[4] = {p.b0.x, p.b0.y, p.b0.z, p.b0.w};
    const float q11[4] = {p.b1.x, p.b1.y, p.b1.z, p.b1.w};
#pragma unroll
    for (int i = 0; i < 4; ++i) {
      const int rm = ng * 4 + i;
      const int f = ((rm >> 2) & 3) ^ ((rm >> 1) & 3);
      const int d = (((kk >> 2) ^ f) << 2) + (kk & 3);
      Bd[rm * 16 + d]        = pk2(q00[i], q01[i]);
      Bd[(rm + 64) * 16 + d] = pk2(q10[i], q11[i]);
    }
  };
  auto stageA = [&](int buf, int k0) {
#pragma unroll
    for (int q = 0; q < 2; ++q)
      gld16(act + aOff[q] + k0, &As[buf][(q * 64 + (tid >> 2)) * 32]);
  };

  f32x4 acc[2][8];
#pragma unroll
  for (int mf = 0; mf < 2; ++mf)
#pragma unroll
    for (int nf = 0; nf < 8; ++nf) acc[mf][nf] = (f32x4)0.f;

  const int rslot = ((l >> 4) ^ ((l >> 2) & 3) ^ ((l >> 1) & 3)) * 8;
  const int arow = (w * 32 + (l & 15)) * 32 + rslot;
  auto mfmaStep = [&](int buf) {
    __builtin_amdgcn_s_setprio(1);
    const bf16x8 a0 = *(const bf16x8*)&As[buf][arow];
    const bf16x8 a1 = *(const bf16x8*)&As[buf][arow + 16 * 32];
#pragma unroll
    for (int nf = 0; nf < 8; ++nf) {
      const bf16x8 b = *(const bf16x8*)&Bs[buf][(nf * 16 + (l & 15)) * 32 + rslot];
      acc[0][nf] = __builtin_amdgcn_mfma_f32_16x16x32_bf16(a0, b, acc[0][nf], 0, 0, 0);
      acc[1][nf] = __builtin_amdgcn_mfma_f32_16x16x32_bf16(a1, b, acc[1][nf], 0, 0, 0);
    }
    __builtin_amdgcn_s_setprio(0);
  };

  Bregs pA, pB;
  loadB(pA, 0);
  stageA(0, 0);
  loadB(pB, 32);
  writeB(0, pA);
  __syncthreads();

  const int NT = IDIM / 32;   // 64, even
  for (int t = 0; t < NT; t += 2) {
    if (t + 2 < NT) loadB(pA, (t + 2) * 32);
    stageA(1, (t + 1) * 32);
    __builtin_amdgcn_sched_barrier(0);
    mfmaStep(0);
    writeB(1, pB);
    __syncthreads();
    if (t + 3 < NT) loadB(pB, (t + 3) * 32);
    if (t + 2 < NT) stageA(0, (t + 2) * 32);
    __builtin_amdgcn_sched_barrier(0);
    mfmaStep(1);
    if (t + 2 < NT) writeB(0, pA);
    __syncthreads();
  }

  const int rbase = m0 + w * 32 + (l >> 4) * 4;
  const int cbase = n0 + (l & 15);
#pragma unroll
  for (int mf = 0; mf < 2; ++mf)
#pragma unroll
    for (int r = 0; r < 4; ++r) {
      const int row = rbase + mf * 16 + r;
      const int slot = rowsv[row];
      if (slot >= 0) {
        const float wgt = rw[slot];
        float* op = out + (size_t)(slot >> 1) * HDIM + cbase;
#pragma unroll
        for (int nf = 0; nf < 8; ++nf)
          atomicAdd(op + nf * 16, acc[mf][nf][r] * wgt);
      }
    }
}

extern "C" void kernel_launch(void* const* d_in, const int* in_sizes, int n_in,
                              void* d_out, int out_size, void* d_ws, size_t ws_size,
                              hipStream_t stream) {
  const float* x  = (const float*)d_in[0];
  const float* Wg = (const float*)d_in[1];
  const float* W1 = (const float*)d_in[2];   // (E, H, I) fp32
  const float* W2 = (const float*)d_in[3];   // (E, I, H) fp32
  const float* W3 = (const float*)d_in[4];   // (E, H, I) fp32
  float* out = (float*)d_out;
  char* ws = (char*)d_ws;
  int*   idx  = (int*)(ws + OFF_IDX);
  float* rw   = (float*)(ws + OFF_RW);
  int*   seg  = (int*)(ws + OFF_SEG);
  int*   rowsv= (int*)(ws + OFF_ROWS);
  unsigned short* xb  = (unsigned short*)(ws + OFF_XB);
  unsigned short* act = (unsigned short*)(ws + OFF_ACT);

  k_router<<<NUM_TOK / 4, 256, 0, stream>>>(x, Wg, xb, idx, rw, out, rowsv);
  k_segscatter<<<1, 256, 0, stream>>>(idx, seg, rowsv);
  k_gemm1<<<dim3(IDIM / 64, MAX_ROWS / 256), 512, 0, stream>>>(xb, W1, W3, seg, rowsv, act);
  k_gemm2<<<dim3(HDIM / 128, MAX_ROWS / 128), 256, 0, stream>>>(act, W2, seg, rowsv, rw, out);
}